// Round 7
// baseline (651.145 us; speedup 1.0000x reference)
//
#include <hip/hip_runtime.h>
#include <math.h>

#define NPTS 12288
#define DIM 64
#define KNN 85
#define KSEL 86          // 85 neighbors + self
#define SAMPLE 2000
#define SSTRIDE 6        // deterministic sample: idx = 6*p, p in [0,2000)
#define GAMMA 0.5f
#define NT 512           // knn block size (8 waves)
#define WPB 8            // waves per block
#define VIT 6            // float4 dist iterations: 6*512*4 = 12288
#define NV 24            // d2 values per lane (VGPR-resident)
#define LCAP 128         // per-wave candidate capacity
#define VCAP 96          // block-level valid-neighbor capacity (~85 expected)
#define PT 64            // pearson tile
#define PPITCH 68        // padded LDS pitch (floats)

// ws layout: [0..36] double accumulators; offset 512: cx[N], cy[N], cz[N]
// acc: [0..4] pearson sums; [5..36] spread slots for local-loss partials

__global__ void prep_kernel(const float* __restrict__ coord,
                            float* __restrict__ cx, float* __restrict__ cy,
                            float* __restrict__ cz) {
  int j = blockIdx.x * 256 + threadIdx.x;
  if (j < NPTS) {
    cx[j] = coord[3 * j];
    cy[j] = coord[3 * j + 1];
    cz[j] = coord[3 * j + 2];
  }
}

// exact wave-local radix select (4x8-bit passes) over NV vals/lane; values of
// 0xFFFFFFFF are padding and skipped (safe: pool always holds >= want reals).
// h = wave-private 256-bin LDS histogram (wave-internal DS ordering only).
template <int NV_>
__device__ __forceinline__ unsigned wave_select4(const unsigned v[NV_], unsigned want,
                                                 unsigned* h, int lane) {
  unsigned prefix = 0;
  #pragma unroll
  for (int pass = 0; pass < 4; ++pass) {
    const int shift = 24 - 8 * pass;
    const unsigned hmask = pass ? (0xFFFFFFFFu << (shift + 8)) : 0u;
    h[lane] = 0; h[lane + 64] = 0; h[lane + 128] = 0; h[lane + 192] = 0;
    __builtin_amdgcn_wave_barrier();
    #pragma unroll
    for (int t = 0; t < NV_; ++t) {
      unsigned u = v[t];
      if (u != 0xFFFFFFFFu && (u & hmask) == prefix)
        atomicAdd(&h[(u >> shift) & 255u], 1u);
    }
    __builtin_amdgcn_wave_barrier();
    unsigned c0 = h[4 * lane], c1 = h[4 * lane + 1];
    unsigned c2 = h[4 * lane + 2], c3 = h[4 * lane + 3];
    unsigned lt = c0 + c1 + c2 + c3;
    unsigned incl = lt;
    #pragma unroll
    for (int off = 1; off < 64; off <<= 1) {
      unsigned t2 = __shfl_up(incl, off, 64);
      if (lane >= off) incl += t2;
    }
    unsigned excl = incl - lt;
    bool has = (lt > 0) && (excl < want) && (want <= incl);
    unsigned bin = 4 * lane, below = excl, cum = excl;
    if (cum + c0 >= want) { bin = 4 * lane; below = cum; }
    else { cum += c0;
      if (cum + c1 >= want) { bin = 4 * lane + 1; below = cum; }
      else { cum += c1;
        if (cum + c2 >= want) { bin = 4 * lane + 2; below = cum; }
        else { cum += c2; bin = 4 * lane + 3; below = cum; } } }
    unsigned long long bal = __ballot(has);
    int src = __ffsll((unsigned long long)bal) - 1;
    bin = __shfl(bin, src, 64);
    below = __shfl(below, src, 64);
    prefix |= bin << shift;
    want -= below;
  }
  return prefix;
}

__global__ __launch_bounds__(256) void pearson_kernel(
    const float* __restrict__ emb, const float* __restrict__ coord,
    double* __restrict__ acc) {
  __shared__ float EpT[DIM][PPITCH];   // transposed: EpT[k][row]
  __shared__ float EqT[DIM][PPITCH];
  __shared__ float Cp[PT][4];
  __shared__ float Cq[PT][4];
  __shared__ double wred[4][5];

  const int tid = threadIdx.x;
  const int tx = tid & 15, ty = tid >> 4;
  const int lane = tid & 63, wv = tid >> 6;
  const int p0 = blockIdx.y * PT, q0 = blockIdx.x * PT;

  for (int e = tid; e < PT * DIM; e += 256) {
    int r = e >> 6, k = e & 63;
    int gp = (p0 + r < SAMPLE ? p0 + r : 0) * SSTRIDE;
    int gq = (q0 + r < SAMPLE ? q0 + r : 0) * SSTRIDE;
    EpT[k][r] = emb[(size_t)gp * DIM + k];
    EqT[k][r] = emb[(size_t)gq * DIM + k];
  }
  if (tid < PT) {
    int g = (p0 + tid < SAMPLE ? p0 + tid : 0) * SSTRIDE;
    Cp[tid][0] = coord[3 * g]; Cp[tid][1] = coord[3 * g + 1]; Cp[tid][2] = coord[3 * g + 2];
  } else if (tid < 2 * PT) {
    int r = tid - PT;
    int g = (q0 + r < SAMPLE ? q0 + r : 0) * SSTRIDE;
    Cq[r][0] = coord[3 * g]; Cq[r][1] = coord[3 * g + 1]; Cq[r][2] = coord[3 * g + 2];
  }
  __syncthreads();

  float s[4][4] = {};
  #pragma unroll 8
  for (int k = 0; k < DIM; ++k) {
    float4 ep = *(const float4*)&EpT[k][4 * ty];
    float4 eq = *(const float4*)&EqT[k][4 * tx];
    float pa[4] = { ep.x, ep.y, ep.z, ep.w };
    float qa[4] = { eq.x, eq.y, eq.z, eq.w };
    #pragma unroll
    for (int a = 0; a < 4; ++a)
      #pragma unroll
      for (int b = 0; b < 4; ++b) {
        float d = pa[a] - qa[b];
        s[a][b] += d * d;
      }
  }

  double se = 0, sc = 0, se2 = 0, sc2 = 0, sec = 0;
  #pragma unroll
  for (int a = 0; a < 4; ++a)
    #pragma unroll
    for (int b = 0; b < 4; ++b) {
      int p = p0 + 4 * ty + a, q = q0 + 4 * tx + b;
      if (p < SAMPLE && q < SAMPLE) {
        float ed = sqrtf(fmaxf(s[a][b], 0.f));
        float dx = Cp[4 * ty + a][0] - Cq[4 * tx + b][0];
        float dy = Cp[4 * ty + a][1] - Cq[4 * tx + b][1];
        float dz = Cp[4 * ty + a][2] - Cq[4 * tx + b][2];
        float cd = sqrtf(fmaxf(dx * dx + dy * dy + dz * dz, 0.f));
        se += (double)ed; sc += (double)cd;
        se2 += (double)ed * ed; sc2 += (double)cd * cd;
        sec += (double)ed * cd;
      }
    }

  double vals[5] = { se, sc, se2, sc2, sec };
  #pragma unroll
  for (int v = 0; v < 5; ++v) {
    #pragma unroll
    for (int off = 32; off > 0; off >>= 1) vals[v] += __shfl_xor(vals[v], off, 64);
  }
  if (lane == 0) {
    #pragma unroll
    for (int v = 0; v < 5; ++v) wred[wv][v] = vals[v];
  }
  __syncthreads();
  if (tid < 5) {
    double sm = wred[0][tid] + wred[1][tid] + wred[2][tid] + wred[3][tid];
    atomicAdd(&acc[tid], sm);
  }
}

__global__ __launch_bounds__(NT, 4) void knn_kernel(
    const float* __restrict__ emb, const float* __restrict__ cx,
    const float* __restrict__ cy, const float* __restrict__ cz,
    double* __restrict__ acc) {
  __shared__ unsigned hist[WPB][256];       // 8 KiB
  __shared__ unsigned nbu[WPB][LCAP];       // 4 KiB
  __shared__ unsigned short nbj[WPB][LCAP]; // 2 KiB
  __shared__ unsigned wcnt[WPB];
  __shared__ unsigned selg;
  __shared__ unsigned vn_u[VCAP];
  __shared__ unsigned short vn_j[VCAP];
  __shared__ unsigned vcnt;

  const int i = blockIdx.x;
  const int tid = threadIdx.x;
  const int lane = tid & 63;
  const int wv = tid >> 6;

  const float qx = cx[i], qy = cy[i], qz = cz[i];
  const float4* CX4 = (const float4*)cx;
  const float4* CY4 = (const float4*)cy;
  const float4* CZ4 = (const float4*)cz;

  // 24 d2 values per thread, uint-cast in VGPRs.
  // unroll 1: keep load staging at 3 float4s so total VGPR stays in the
  // 64-class (R6 lesson: full unroll hoists 18 float4s -> spill at cap 64).
  unsigned d2b[NV];
  #pragma unroll 1
  for (int it = 0; it < VIT; ++it) {
    int idx = it * NT + tid;
    float4 x4 = CX4[idx], y4 = CY4[idx], z4 = CZ4[idx];
    float dx, dy, dz;
    dx = qx - x4.x; dy = qy - y4.x; dz = qz - z4.x;
    d2b[4 * it + 0] = __float_as_uint(dx * dx + dy * dy + dz * dz);
    dx = qx - x4.y; dy = qy - y4.y; dz = qz - z4.y;
    d2b[4 * it + 1] = __float_as_uint(dx * dx + dy * dy + dz * dz);
    dx = qx - x4.z; dy = qy - y4.z; dz = qz - z4.z;
    d2b[4 * it + 2] = __float_as_uint(dx * dx + dy * dy + dz * dz);
    dx = qx - x4.w; dy = qy - y4.w; dz = qz - z4.w;
    d2b[4 * it + 3] = __float_as_uint(dx * dx + dy * dy + dz * dz);
  }
  const float4 ei4 = ((const float4*)(emb + (size_t)i * DIM))[lane & 15];

  // ---- VALU pre-filter: per-lane two smallest (uint order == float order) ----
  unsigned m1 = 0xFFFFFFFFu, m2 = 0xFFFFFFFFu;
  #pragma unroll
  for (int t = 0; t < NV; ++t) {
    unsigned u = d2b[t];
    unsigned hi = u > m1 ? u : m1;
    m1 = u < m1 ? u : m1;
    m2 = hi < m2 ? hi : m2;
  }
  // M2 = wave-max of 2nd-smallest: >=128 values <= M2, so wave-86th <= M2
  unsigned M2 = m2;
  #pragma unroll
  for (int off = 32; off > 0; off >>= 1) {
    unsigned t2 = __shfl_xor((int)M2, off, 64);
    M2 = t2 > M2 ? t2 : M2;
  }
  const float M2f = __uint_as_float(M2);
  const float sbin = 256.0f / fmaxf(M2f, 1e-30f);

  // ---- single linear-binned histogram over filtered values ----
  unsigned* h = hist[wv];
  h[lane] = 0; h[lane + 64] = 0; h[lane + 128] = 0; h[lane + 192] = 0;
  __builtin_amdgcn_wave_barrier();
  #pragma unroll
  for (int t = 0; t < NV; ++t) {
    unsigned u = d2b[t];
    if (u <= M2) {
      int b = (int)(__uint_as_float(u) * sbin);
      b = b > 255 ? 255 : b;
      atomicAdd(&h[b], 1u);
    }
  }
  __builtin_amdgcn_wave_barrier();
  unsigned c0 = h[4 * lane], c1 = h[4 * lane + 1];
  unsigned c2 = h[4 * lane + 2], c3 = h[4 * lane + 3];
  unsigned lt = c0 + c1 + c2 + c3;
  unsigned incl = lt;
  #pragma unroll
  for (int off = 1; off < 64; off <<= 1) {
    unsigned t2 = __shfl_up(incl, off, 64);
    if (lane >= off) incl += t2;
  }
  unsigned excl = incl - lt;
  bool has = (lt > 0) && (excl < KSEL) && (KSEL <= incl);
  unsigned bin = 4 * lane, cum = excl;
  if (cum + c0 >= KSEL) { bin = 4 * lane; }
  else { cum += c0;
    if (cum + c1 >= KSEL) { bin = 4 * lane + 1; }
    else { cum += c1;
      if (cum + c2 >= KSEL) { bin = 4 * lane + 2; }
      else { bin = 4 * lane + 3; } } }
  unsigned long long bal = __ballot(has);
  int src = __ffsll((unsigned long long)bal) - 1;
  unsigned bsel = __shfl((int)bin, src, 64);
  // inclusive upper edge of the selected bucket (2-ulp safety margin up)
  float Uf = (float)(bsel + 1) * (M2f * (1.0f / 256.0f)) * 1.000002f;
  unsigned U = __float_as_uint(Uf);

  // ---- guarded atomic append of candidates u <= U ----
  if (lane == 0) wcnt[wv] = 0;
  if (tid == 0) vcnt = 0;
  __builtin_amdgcn_wave_barrier();
  #pragma unroll
  for (int t = 0; t < NV; ++t) {
    unsigned u = d2b[t];
    if (u <= U) {
      unsigned pos = atomicAdd(&wcnt[wv], 1u);
      if (pos < LCAP) {
        nbu[wv][pos] = u;
        int it = t >> 2, c = t & 3;
        nbj[wv][pos] = (unsigned short)(4 * (it * NT + tid) + c);
      }
    }
  }
  __syncthreads();   // barrier 1: lists + vcnt=0 visible

  // ---- wave 0: exact global 86th among the union of per-wave candidate sets --
  if (wv == 0) {
    unsigned mv[2 * WPB];
    #pragma unroll
    for (int w = 0; w < WPB; ++w) {
      unsigned mw = wcnt[w] < LCAP ? wcnt[w] : LCAP;
      mv[2 * w]     = ((unsigned)lane < mw)      ? nbu[w][lane]      : 0xFFFFFFFFu;
      mv[2 * w + 1] = ((unsigned)lane + 64 < mw) ? nbu[w][lane + 64] : 0xFFFFFFFFu;
    }
    unsigned t = wave_select4<2 * WPB>(mv, KSEL, hist[0], lane);
    if (lane == 0) selg = t;
  }
  __syncthreads();   // barrier 2: threshold visible
  const unsigned thrg = selg;

  // ---- compact the true 85 neighbors into one block-level list ----
  const int mw = (int)(wcnt[wv] < LCAP ? wcnt[wv] : LCAP);
  for (int n = lane; n < mw; n += 64) {
    unsigned u = nbu[wv][n];
    int j = (int)nbj[wv][n];
    if (u <= thrg && j != i) {
      unsigned p = atomicAdd(&vcnt, 1u);
      if (p < VCAP) { vn_u[p] = u; vn_j[p] = (unsigned short)j; }
    }
  }
  __syncthreads();   // barrier 3: valid list visible
  const int tot = (int)(vcnt < VCAP ? vcnt : VCAP);

  // ---- loss: 32 neighbors per block-iteration (8 waves x 4 quarters) ----
  const int q = lane >> 4;
  const int l16 = lane & 15;
  float lsum = 0.f;
  for (int base = wv * 4; base < tot; base += 32) {   // wave-uniform trip count
    int idx = base + q;
    bool valid = idx < tot;
    unsigned u = 0; int j = 0;
    if (valid) { u = vn_u[idx]; j = (int)vn_j[idx]; }
    float s = 0.f;
    if (valid) {
      float4 e4 = ((const float4*)(emb + (size_t)j * DIM))[l16];
      float d0 = ei4.x - e4.x, d1 = ei4.y - e4.y;
      float d2 = ei4.z - e4.z, d3 = ei4.w - e4.w;
      s = d0 * d0 + d1 * d1 + d2 * d2 + d3 * d3;
    }
    s += __shfl_xor(s, 1, 64);
    s += __shfl_xor(s, 2, 64);
    s += __shfl_xor(s, 4, 64);
    s += __shfl_xor(s, 8, 64);
    if (valid && l16 == 0) {
      float td = sqrtf(__uint_as_float(u));
      float pd = sqrtf(fmaxf(s, 0.f));
      float diff = pd - td;
      lsum += diff * diff * expf(-GAMMA * td);
    }
  }
  #pragma unroll
  for (int off = 32; off > 0; off >>= 1) lsum += __shfl_xor(lsum, off, 64);
  if (lane == 0) atomicAdd(&acc[5 + (blockIdx.x & 3) * 8 + wv], (double)lsum);
}

__global__ void finalize_kernel(const double* __restrict__ acc,
                                float* __restrict__ out) {
  double M = (double)SAMPLE * (double)SAMPLE;
  double med = acc[0] / M, mcd = acc[1] / M;
  double ve = acc[2] / M - med * med;
  double vc = acc[3] / M - mcd * mcd;
  double es = sqrt(ve + 1e-8);
  double cs = sqrt(vc + 1e-8);
  double cov = acc[4] / M - med * mcd;
  double pearson = cov / (es * cs + 1e-8);
  double lsum = 0.0;
  for (int s = 5; s < 37; ++s) lsum += acc[s];
  double local = lsum / ((double)NPTS * (double)KNN);
  out[0] = (float)((1.0 - pearson) + 0.5 * local);
}

extern "C" void kernel_launch(void* const* d_in, const int* in_sizes, int n_in,
                              void* d_out, int out_size, void* d_ws, size_t ws_size,
                              hipStream_t stream) {
  const float* emb = (const float*)d_in[0];    // (12288, 64) f32
  const float* coord = (const float*)d_in[1];  // (12288, 3) f32
  double* acc = (double*)d_ws;
  float* cx = (float*)((char*)d_ws + 512);     // 16B-aligned SoA coords
  float* cy = cx + NPTS;
  float* cz = cy + NPTS;

  hipMemsetAsync(d_ws, 0, 37 * sizeof(double), stream);

  prep_kernel<<<(NPTS + 255) / 256, 256, 0, stream>>>(coord, cx, cy, cz);

  pearson_kernel<<<dim3((SAMPLE + PT - 1) / PT, (SAMPLE + PT - 1) / PT), 256, 0, stream>>>(
      emb, coord, acc);

  knn_kernel<<<NPTS, NT, 0, stream>>>(emb, cx, cy, cz, acc);

  finalize_kernel<<<1, 1, 0, stream>>>(acc, (float*)d_out);
}

// Round 8
// 352.931 us; speedup vs baseline: 1.8450x; 1.8450x over previous
//
#include <hip/hip_runtime.h>
#include <math.h>

#define NPTS 12288
#define DIM 64
#define KNN 85
#define KSEL 86          // 85 neighbors + self
#define SAMPLE 2000
#define SSTRIDE 6        // deterministic sample: idx = 6*p, p in [0,2000)
#define GAMMA 0.5f
#define NT 256           // knn block size (4 waves) -- R5 proven no-spill shape
#define WPB 4            // waves per block
#define VIT 12           // float4 dist iterations: 12*256*4 = 12288
#define NV 48            // d2 values per lane; MUST stay fully unrolled
#define LCAP 128         // per-wave candidate capacity (~88-92 expected)
#define VCAP 96          // block-level valid-neighbor capacity (exactly <=85)
#define PT 64            // pearson tile
#define PPITCH 68        // padded LDS pitch (floats)

// ws layout: [0..36] double accumulators; offset 512: cx[N], cy[N], cz[N]
// acc: [0..4] pearson sums; [5..36] spread slots for local-loss partials

__global__ void prep_kernel(const float* __restrict__ coord,
                            float* __restrict__ cx, float* __restrict__ cy,
                            float* __restrict__ cz) {
  int j = blockIdx.x * 256 + threadIdx.x;
  if (j < NPTS) {
    cx[j] = coord[3 * j];
    cy[j] = coord[3 * j + 1];
    cz[j] = coord[3 * j + 2];
  }
}

// exact wave-local radix select (4x8-bit passes) over NV_ vals/lane; values of
// 0xFFFFFFFF are padding and skipped (safe: pool always holds >= want reals).
// h = wave-private 256-bin LDS histogram (wave-internal DS ordering only).
template <int NV_>
__device__ __forceinline__ unsigned wave_select4(const unsigned v[NV_], unsigned want,
                                                 unsigned* h, int lane) {
  unsigned prefix = 0;
  #pragma unroll
  for (int pass = 0; pass < 4; ++pass) {
    const int shift = 24 - 8 * pass;
    const unsigned hmask = pass ? (0xFFFFFFFFu << (shift + 8)) : 0u;
    h[lane] = 0; h[lane + 64] = 0; h[lane + 128] = 0; h[lane + 192] = 0;
    __builtin_amdgcn_wave_barrier();
    #pragma unroll
    for (int t = 0; t < NV_; ++t) {
      unsigned u = v[t];
      if (u != 0xFFFFFFFFu && (u & hmask) == prefix)
        atomicAdd(&h[(u >> shift) & 255u], 1u);
    }
    __builtin_amdgcn_wave_barrier();
    unsigned c0 = h[4 * lane], c1 = h[4 * lane + 1];
    unsigned c2 = h[4 * lane + 2], c3 = h[4 * lane + 3];
    unsigned lt = c0 + c1 + c2 + c3;
    unsigned incl = lt;
    #pragma unroll
    for (int off = 1; off < 64; off <<= 1) {
      unsigned t2 = __shfl_up(incl, off, 64);
      if (lane >= off) incl += t2;
    }
    unsigned excl = incl - lt;
    bool has = (lt > 0) && (excl < want) && (want <= incl);
    unsigned bin = 4 * lane, below = excl, cum = excl;
    if (cum + c0 >= want) { bin = 4 * lane; below = cum; }
    else { cum += c0;
      if (cum + c1 >= want) { bin = 4 * lane + 1; below = cum; }
      else { cum += c1;
        if (cum + c2 >= want) { bin = 4 * lane + 2; below = cum; }
        else { cum += c2; bin = 4 * lane + 3; below = cum; } } }
    unsigned long long bal = __ballot(has);
    int src = __ffsll((unsigned long long)bal) - 1;
    bin = __shfl(bin, src, 64);
    below = __shfl(below, src, 64);
    prefix |= bin << shift;
    want -= below;
  }
  return prefix;
}

__global__ __launch_bounds__(256) void pearson_kernel(
    const float* __restrict__ emb, const float* __restrict__ coord,
    double* __restrict__ acc) {
  __shared__ float EpT[DIM][PPITCH];   // transposed: EpT[k][row]
  __shared__ float EqT[DIM][PPITCH];
  __shared__ float Cp[PT][4];
  __shared__ float Cq[PT][4];
  __shared__ double wred[4][5];

  const int tid = threadIdx.x;
  const int tx = tid & 15, ty = tid >> 4;
  const int lane = tid & 63, wv = tid >> 6;
  const int p0 = blockIdx.y * PT, q0 = blockIdx.x * PT;

  for (int e = tid; e < PT * DIM; e += 256) {
    int r = e >> 6, k = e & 63;
    int gp = (p0 + r < SAMPLE ? p0 + r : 0) * SSTRIDE;
    int gq = (q0 + r < SAMPLE ? q0 + r : 0) * SSTRIDE;
    EpT[k][r] = emb[(size_t)gp * DIM + k];
    EqT[k][r] = emb[(size_t)gq * DIM + k];
  }
  if (tid < PT) {
    int g = (p0 + tid < SAMPLE ? p0 + tid : 0) * SSTRIDE;
    Cp[tid][0] = coord[3 * g]; Cp[tid][1] = coord[3 * g + 1]; Cp[tid][2] = coord[3 * g + 2];
  } else if (tid < 2 * PT) {
    int r = tid - PT;
    int g = (q0 + r < SAMPLE ? q0 + r : 0) * SSTRIDE;
    Cq[r][0] = coord[3 * g]; Cq[r][1] = coord[3 * g + 1]; Cq[r][2] = coord[3 * g + 2];
  }
  __syncthreads();

  float s[4][4] = {};
  #pragma unroll 8
  for (int k = 0; k < DIM; ++k) {
    float4 ep = *(const float4*)&EpT[k][4 * ty];
    float4 eq = *(const float4*)&EqT[k][4 * tx];
    float pa[4] = { ep.x, ep.y, ep.z, ep.w };
    float qa[4] = { eq.x, eq.y, eq.z, eq.w };
    #pragma unroll
    for (int a = 0; a < 4; ++a)
      #pragma unroll
      for (int b = 0; b < 4; ++b) {
        float d = pa[a] - qa[b];
        s[a][b] += d * d;
      }
  }

  double se = 0, sc = 0, se2 = 0, sc2 = 0, sec = 0;
  #pragma unroll
  for (int a = 0; a < 4; ++a)
    #pragma unroll
    for (int b = 0; b < 4; ++b) {
      int p = p0 + 4 * ty + a, q = q0 + 4 * tx + b;
      if (p < SAMPLE && q < SAMPLE) {
        float ed = sqrtf(fmaxf(s[a][b], 0.f));
        float dx = Cp[4 * ty + a][0] - Cq[4 * tx + b][0];
        float dy = Cp[4 * ty + a][1] - Cq[4 * tx + b][1];
        float dz = Cp[4 * ty + a][2] - Cq[4 * tx + b][2];
        float cd = sqrtf(fmaxf(dx * dx + dy * dy + dz * dz, 0.f));
        se += (double)ed; sc += (double)cd;
        se2 += (double)ed * ed; sc2 += (double)cd * cd;
        sec += (double)ed * cd;
      }
    }

  double vals[5] = { se, sc, se2, sc2, sec };
  #pragma unroll
  for (int v = 0; v < 5; ++v) {
    #pragma unroll
    for (int off = 32; off > 0; off >>= 1) vals[v] += __shfl_xor(vals[v], off, 64);
  }
  if (lane == 0) {
    #pragma unroll
    for (int v = 0; v < 5; ++v) wred[wv][v] = vals[v];
  }
  __syncthreads();
  if (tid < 5) {
    double sm = wred[0][tid] + wred[1][tid] + wred[2][tid] + wred[3][tid];
    atomicAdd(&acc[tid], sm);
  }
}

__global__ __launch_bounds__(NT) void knn_kernel(
    const float* __restrict__ emb, const float* __restrict__ cx,
    const float* __restrict__ cy, const float* __restrict__ cz,
    double* __restrict__ acc) {
  __shared__ unsigned hist[WPB][256];       // 4 KiB
  __shared__ unsigned nbu[WPB][LCAP];       // 2 KiB
  __shared__ unsigned short nbj[WPB][LCAP]; // 1 KiB
  __shared__ unsigned wcnt[WPB];
  __shared__ unsigned selg;
  __shared__ unsigned vn_u[VCAP];
  __shared__ unsigned short vn_j[VCAP];
  __shared__ unsigned vcnt;

  const int i = blockIdx.x;
  const int tid = threadIdx.x;
  const int lane = tid & 63;
  const int wv = tid >> 6;

  const float qx = cx[i], qy = cy[i], qz = cz[i];
  const float4* CX4 = (const float4*)cx;
  const float4* CY4 = (const float4*)cy;
  const float4* CZ4 = (const float4*)cz;

  // 48 d2 values per thread in VGPRs. FULL unroll is mandatory: constant
  // indices -> register promotion (R7 lesson: unroll 1 => scratch, 593 MB
  // of spill traffic). No min-waves launch bound (R6 lesson: cap => spill).
  unsigned d2b[NV];
  #pragma unroll
  for (int it = 0; it < VIT; ++it) {
    int idx = it * NT + tid;
    float4 x4 = CX4[idx], y4 = CY4[idx], z4 = CZ4[idx];
    float dx, dy, dz;
    dx = qx - x4.x; dy = qy - y4.x; dz = qz - z4.x;
    d2b[4 * it + 0] = __float_as_uint(dx * dx + dy * dy + dz * dz);
    dx = qx - x4.y; dy = qy - y4.y; dz = qz - z4.y;
    d2b[4 * it + 1] = __float_as_uint(dx * dx + dy * dy + dz * dz);
    dx = qx - x4.z; dy = qy - y4.z; dz = qz - z4.z;
    d2b[4 * it + 2] = __float_as_uint(dx * dx + dy * dy + dz * dz);
    dx = qx - x4.w; dy = qy - y4.w; dz = qz - z4.w;
    d2b[4 * it + 3] = __float_as_uint(dx * dx + dy * dy + dz * dz);
  }
  const float4 ei4 = ((const float4*)(emb + (size_t)i * DIM))[lane & 15];

  // ---- VALU pre-filter: per-lane two smallest (uint order == float order) ----
  unsigned m1 = 0xFFFFFFFFu, m2 = 0xFFFFFFFFu;
  #pragma unroll
  for (int t = 0; t < NV; ++t) {
    unsigned u = d2b[t];
    unsigned hi = u > m1 ? u : m1;
    m1 = u < m1 ? u : m1;
    m2 = hi < m2 ? hi : m2;
  }
  // M2 = wave-max of 2nd-smallest: >=128 values <= M2, so wave-86th <= M2
  unsigned M2 = m2;
  #pragma unroll
  for (int off = 32; off > 0; off >>= 1) {
    unsigned t2 = __shfl_xor((int)M2, off, 64);
    M2 = t2 > M2 ? t2 : M2;
  }
  const float M2f = __uint_as_float(M2);
  const float sbin = 256.0f / fmaxf(M2f, 1e-30f);

  // ---- single linear-binned histogram over filtered values (~6 atomics/lane) --
  unsigned* h = hist[wv];
  h[lane] = 0; h[lane + 64] = 0; h[lane + 128] = 0; h[lane + 192] = 0;
  __builtin_amdgcn_wave_barrier();
  #pragma unroll
  for (int t = 0; t < NV; ++t) {
    unsigned u = d2b[t];
    if (u <= M2) {
      int b = (int)(__uint_as_float(u) * sbin);
      b = b > 255 ? 255 : b;
      atomicAdd(&h[b], 1u);
    }
  }
  __builtin_amdgcn_wave_barrier();
  unsigned c0 = h[4 * lane], c1 = h[4 * lane + 1];
  unsigned c2 = h[4 * lane + 2], c3 = h[4 * lane + 3];
  unsigned lt = c0 + c1 + c2 + c3;
  unsigned incl = lt;
  #pragma unroll
  for (int off = 1; off < 64; off <<= 1) {
    unsigned t2 = __shfl_up(incl, off, 64);
    if (lane >= off) incl += t2;
  }
  unsigned excl = incl - lt;
  bool has = (lt > 0) && (excl < KSEL) && (KSEL <= incl);
  unsigned bin = 4 * lane, cum = excl;
  if (cum + c0 >= KSEL) { bin = 4 * lane; }
  else { cum += c0;
    if (cum + c1 >= KSEL) { bin = 4 * lane + 1; }
    else { cum += c1;
      if (cum + c2 >= KSEL) { bin = 4 * lane + 2; }
      else { bin = 4 * lane + 3; } } }
  unsigned long long bal = __ballot(has);
  int src = __ffsll((unsigned long long)bal) - 1;
  unsigned bsel = __shfl((int)bin, src, 64);
  // inclusive upper edge of the selected bucket (2-ulp safety margin up)
  float Uf = (float)(bsel + 1) * (M2f * (1.0f / 256.0f)) * 1.000002f;
  unsigned U = __float_as_uint(Uf);

  // ---- guarded atomic append of candidates u <= U (~88-92 per wave) ----
  if (lane == 0) wcnt[wv] = 0;
  if (tid == 0) vcnt = 0;
  __builtin_amdgcn_wave_barrier();
  #pragma unroll
  for (int t = 0; t < NV; ++t) {
    unsigned u = d2b[t];
    if (u <= U) {
      unsigned pos = atomicAdd(&wcnt[wv], 1u);
      if (pos < LCAP) {
        nbu[wv][pos] = u;
        int it = t >> 2, c = t & 3;
        nbj[wv][pos] = (unsigned short)(4 * (it * NT + tid) + c);
      }
    }
  }
  __syncthreads();   // barrier 1: lists + vcnt=0 visible

  // ---- wave 0: exact global 86th among the union of per-wave candidate sets --
  if (wv == 0) {
    unsigned mv[2 * WPB];
    #pragma unroll
    for (int w = 0; w < WPB; ++w) {
      unsigned mw = wcnt[w] < LCAP ? wcnt[w] : LCAP;
      mv[2 * w]     = ((unsigned)lane < mw)      ? nbu[w][lane]      : 0xFFFFFFFFu;
      mv[2 * w + 1] = ((unsigned)lane + 64 < mw) ? nbu[w][lane + 64] : 0xFFFFFFFFu;
    }
    unsigned t = wave_select4<2 * WPB>(mv, KSEL, hist[0], lane);
    if (lane == 0) selg = t;
  }
  __syncthreads();   // barrier 2: threshold visible
  const unsigned thrg = selg;

  // ---- compact the true 85 neighbors into one block-level list ----
  const int mw = (int)(wcnt[wv] < LCAP ? wcnt[wv] : LCAP);
  for (int n = lane; n < mw; n += 64) {
    unsigned u = nbu[wv][n];
    int j = (int)nbj[wv][n];
    if (u <= thrg && j != i) {
      unsigned p = atomicAdd(&vcnt, 1u);
      if (p < VCAP) { vn_u[p] = u; vn_j[p] = (unsigned short)j; }
    }
  }
  __syncthreads();   // barrier 3: valid list visible
  const int tot = (int)(vcnt < VCAP ? vcnt : VCAP);

  // ---- loss: 16 neighbors per block-iteration (4 waves x 4 quarters) ----
  const int q = lane >> 4;
  const int l16 = lane & 15;
  float lsum = 0.f;
  for (int base = wv * 4; base < tot; base += 16) {   // wave-uniform trip count
    int idx = base + q;
    bool valid = idx < tot;
    unsigned u = 0; int j = 0;
    if (valid) { u = vn_u[idx]; j = (int)vn_j[idx]; }
    float s = 0.f;
    if (valid) {
      float4 e4 = ((const float4*)(emb + (size_t)j * DIM))[l16];
      float d0 = ei4.x - e4.x, d1 = ei4.y - e4.y;
      float d2 = ei4.z - e4.z, d3 = ei4.w - e4.w;
      s = d0 * d0 + d1 * d1 + d2 * d2 + d3 * d3;
    }
    s += __shfl_xor(s, 1, 64);
    s += __shfl_xor(s, 2, 64);
    s += __shfl_xor(s, 4, 64);
    s += __shfl_xor(s, 8, 64);
    if (valid && l16 == 0) {
      float td = sqrtf(__uint_as_float(u));
      float pd = sqrtf(fmaxf(s, 0.f));
      float diff = pd - td;
      lsum += diff * diff * expf(-GAMMA * td);
    }
  }
  #pragma unroll
  for (int off = 32; off > 0; off >>= 1) lsum += __shfl_xor(lsum, off, 64);
  if (lane == 0) atomicAdd(&acc[5 + (blockIdx.x & 7) * 4 + wv], (double)lsum);
}

__global__ void finalize_kernel(const double* __restrict__ acc,
                                float* __restrict__ out) {
  double M = (double)SAMPLE * (double)SAMPLE;
  double med = acc[0] / M, mcd = acc[1] / M;
  double ve = acc[2] / M - med * med;
  double vc = acc[3] / M - mcd * mcd;
  double es = sqrt(ve + 1e-8);
  double cs = sqrt(vc + 1e-8);
  double cov = acc[4] / M - med * mcd;
  double pearson = cov / (es * cs + 1e-8);
  double lsum = 0.0;
  for (int s = 5; s < 37; ++s) lsum += acc[s];
  double local = lsum / ((double)NPTS * (double)KNN);
  out[0] = (float)((1.0 - pearson) + 0.5 * local);
}

extern "C" void kernel_launch(void* const* d_in, const int* in_sizes, int n_in,
                              void* d_out, int out_size, void* d_ws, size_t ws_size,
                              hipStream_t stream) {
  const float* emb = (const float*)d_in[0];    // (12288, 64) f32
  const float* coord = (const float*)d_in[1];  // (12288, 3) f32
  double* acc = (double*)d_ws;
  float* cx = (float*)((char*)d_ws + 512);     // 16B-aligned SoA coords
  float* cy = cx + NPTS;
  float* cz = cy + NPTS;

  hipMemsetAsync(d_ws, 0, 37 * sizeof(double), stream);

  prep_kernel<<<(NPTS + 255) / 256, 256, 0, stream>>>(coord, cx, cy, cz);

  pearson_kernel<<<dim3((SAMPLE + PT - 1) / PT, (SAMPLE + PT - 1) / PT), 256, 0, stream>>>(
      emb, coord, acc);

  knn_kernel<<<NPTS, NT, 0, stream>>>(emb, cx, cy, cz, acc);

  finalize_kernel<<<1, 1, 0, stream>>>(acc, (float*)d_out);
}